// Round 1
// baseline (102.397 us; speedup 1.0000x reference)
//
#include <hip/hip_runtime.h>

// Problem constants (fixed by setup_inputs).
#define B_   16
#define C_   3
#define H_   512
#define W_   1024
#define MW   256          // mask_width
#define K    11
#define PAD  5
#define TH   32
#define TW   32
#define SH   (TH + K - 1) // 42
#define SW   (TW + K - 1) // 42
#define SSTR 44           // LDS row stride for staged tiles (avoid pow2)

__global__ __launch_bounds__(256) void ssim_main(const float* __restrict__ img1,
                                                 const float* __restrict__ img2,
                                                 const int*   __restrict__ mask_pos,
                                                 float*       __restrict__ accum) {
    __shared__ float sm1[SH][SSTR];
    __shared__ float sm2[SH][SSTR];
    __shared__ float h1[SH][TW], h2[SH][TW], h11[SH][TW], h22[SH][TW], h12[SH][TW];
    __shared__ float red[256];

    // Gaussian weights, computed like numpy: double exp -> normalize -> float.
    float g[K];
    {
        double gd[K]; double s = 0.0;
        #pragma unroll
        for (int i = 0; i < K; ++i) { double d = (double)(i - K / 2); gd[i] = exp(-(d * d) / 4.5); s += gd[i]; }
        #pragma unroll
        for (int i = 0; i < K; ++i) g[i] = (float)(gd[i] / s);
    }

    const int blk   = blockIdx.x;
    const int tileX = blk % (MW / TW);              // 8
    const int tileY = (blk / (MW / TW)) % (H_ / TH); // 16
    const int bc    = blk / ((MW / TW) * (H_ / TH)); // 48
    const int b     = bc / C_;
    const int ch    = bc % C_;

    int s0 = mask_pos[b];
    s0 = min(max(s0, 0), W_ - MW);

    const float* __restrict__ p1 = img1 + (size_t)(b * C_ + ch) * H_ * W_;
    const float* __restrict__ p2 = img2 + (size_t)(b * C_ + ch) * H_ * W_;

    const int tid = threadIdx.x;
    const int y0  = tileY * TH - PAD;
    const int x0  = tileX * TW - PAD;

    // Stage m1, m2 tile + halo (zero padding outside the crop).
    for (int i = tid; i < SH * SW; i += 256) {
        const int r = i / SW, c = i % SW;
        const int gy = y0 + r, gx = x0 + c;
        float a = 0.f, bb = 0.f;
        if (gy >= 0 && gy < H_ && gx >= 0 && gx < MW) {
            const size_t off = (size_t)gy * W_ + (size_t)(s0 + gx);
            a  = p1[off];
            bb = p2[off];
        }
        sm1[r][c] = a;
        sm2[r][c] = bb;
    }
    __syncthreads();

    // Horizontal 11-tap pass over 5 fields.
    for (int i = tid; i < SH * TW; i += 256) {
        const int r = i / TW, c = i % TW;
        float s1 = 0.f, s2 = 0.f, s11 = 0.f, s22 = 0.f, s12 = 0.f;
        #pragma unroll
        for (int dx = 0; dx < K; ++dx) {
            const float a  = sm1[r][c + dx];
            const float bb = sm2[r][c + dx];
            const float gw = g[dx];
            s1  += gw * a;
            s2  += gw * bb;
            s11 += gw * a * a;
            s22 += gw * bb * bb;
            s12 += gw * a * bb;
        }
        h1[r][c] = s1; h2[r][c] = s2; h11[r][c] = s11; h22[r][c] = s22; h12[r][c] = s12;
    }
    __syncthreads();

    // Vertical 11-tap pass + SSIM formula; per-thread partial sum.
    float part = 0.f;
    for (int i = tid; i < TH * TW; i += 256) {
        const int r = i / TW, c = i % TW;
        float mu1 = 0.f, mu2 = 0.f, x11 = 0.f, x22 = 0.f, x12 = 0.f;
        #pragma unroll
        for (int dy = 0; dy < K; ++dy) {
            const float gw = g[dy];
            mu1 += gw * h1[r + dy][c];
            mu2 += gw * h2[r + dy][c];
            x11 += gw * h11[r + dy][c];
            x22 += gw * h22[r + dy][c];
            x12 += gw * h12[r + dy][c];
        }
        const float mu1s = mu1 * mu1, mu2s = mu2 * mu2, mu12 = mu1 * mu2;
        const float sig1 = x11 - mu1s, sig2 = x22 - mu2s, sig12 = x12 - mu12;
        const float C1v = 1e-4f, C2v = 9e-4f, epsv = 1e-5f;
        const float num = (2.f * mu12 + C1v) * (2.f * sig12 + C2v) + epsv;
        const float den = (mu1s + mu2s + C1v) * (sig1 + sig2 + C2v) + epsv;
        part += num / den;
    }

    // Block reduction -> one atomic per block.
    red[tid] = part;
    __syncthreads();
    for (int off = 128; off > 0; off >>= 1) {
        if (tid < off) red[tid] += red[tid + off];
        __syncthreads();
    }
    if (tid == 0) atomicAdd(accum, red[0]);
}

__global__ void ssim_final(const float* __restrict__ accum, float* __restrict__ out) {
    out[0] = 1.0f - accum[0] * (1.0f / (float)(B_ * C_ * H_ * MW));
}

extern "C" void kernel_launch(void* const* d_in, const int* in_sizes, int n_in,
                              void* d_out, int out_size, void* d_ws, size_t ws_size,
                              hipStream_t stream) {
    const float* img1 = (const float*)d_in[0];
    const float* img2 = (const float*)d_in[1];
    const int*   pos  = (const int*)d_in[2];
    float* out = (float*)d_out;
    float* acc = (float*)d_ws;

    hipMemsetAsync(acc, 0, sizeof(float), stream);

    const int nblocks = (MW / TW) * (H_ / TH) * B_ * C_; // 6144
    ssim_main<<<nblocks, 256, 0, stream>>>(img1, img2, pos, acc);
    ssim_final<<<1, 1, 0, stream>>>(acc, out);
}

// Round 3
// 71.744 us; speedup vs baseline: 1.4273x; 1.4273x over previous
//
#include <hip/hip_runtime.h>

// Problem constants (fixed by setup_inputs).
#define B_    16
#define C_    3
#define H_    512
#define W_    1024
#define MW    256          // mask_width
#define RS    34           // output rows per wave-strip
#define NRS   16           // row strips: 16*34 = 544 >= 512 (last strip ragged)
#define NROWS 44           // input rows streamed per strip (= RS + 10)

__global__ __launch_bounds__(256) void ssim_main(const float* __restrict__ img1,
                                                 const float* __restrict__ img2,
                                                 const int*   __restrict__ mask_pos,
                                                 float*       __restrict__ accum) {
    // Gaussian weights = float64 exp/normalize, precomputed to float literals.
    constexpr float G[11] = {
        0.00102838f, 0.00759876f, 0.03600077f, 0.10936070f, 0.21300553f,
        0.26601173f, 0.21300553f, 0.10936070f, 0.03600077f, 0.00759876f,
        0.00102838f };

    // Per-wave DOUBLE-BUFFERED 74-col {img1,img2} row ring. 5 KB total.
    __shared__ float2 rowbuf[4][2][80];

    const int tid  = threadIdx.x;
    const int w    = tid >> 6;
    const int lane = tid & 63;

    const int blk   = blockIdx.x;
    const int strip = blk & (NRS - 1);   // row strip 0..15
    const int bc    = blk >> 4;          // (b,ch) 0..47
    const int b     = bc / 3;

    int s0 = mask_pos[b];
    s0 = min(max(s0, 0), W_ - MW);

    const float* __restrict__ p1 = img1 + (size_t)bc * (H_ * W_);
    const float* __restrict__ p2 = img2 + (size_t)bc * (H_ * W_);

    const int y0  = strip * RS;
    const int sx0 = w << 6;              // column strip base within crop
    const int cxm = sx0 - 5 + lane;      // main staged column (crop coords)
    const int cxh = sx0 + 59 + lane;     // halo staged column (lane < 10)
    const bool vm = (cxm >= 0) && (cxm < MW);
    const bool vh = (lane < 10) && (cxh < MW);
    const int gxm = s0 + cxm;
    const int gxh = s0 + cxh;

    // 11 pending output rows x 5 conv fields, statically indexed registers.
    float acc[11][5];
    #pragma unroll
    for (int s = 0; s < 11; ++s)
        #pragma unroll
        for (int f = 0; f < 5; ++f) acc[s][f] = 0.f;

    float psum = 0.f;

    // Prologue: stage streamed row i=0 (input row y0-5) into parity 0.
    {
        const int r = y0 - 5;
        float a0 = 0.f, b0 = 0.f, a1 = 0.f, b1 = 0.f;
        if (r >= 0) {                    // r < H_ always holds here
            const int ro = r * W_;
            if (vm) { a0 = p1[ro + gxm]; b0 = p2[ro + gxm]; }
            if (vh) { a1 = p1[ro + gxh]; b1 = p2[ro + gxh]; }
        }
        rowbuf[w][0][lane] = make_float2(a0, b0);
        if (lane < 10) rowbuf[w][0][64 + lane] = make_float2(a1, b1);
    }
    // Compiler fence: no DS op may cross (hw DS pipe is in-order per wave).
    __builtin_amdgcn_sched_barrier(0);
    __builtin_amdgcn_wave_barrier();
    __builtin_amdgcn_sched_barrier(0);

    for (int half = 0; half < 2; ++half) {
        #pragma unroll
        for (int j = 0; j < 22; ++j) {
            const int i   = half * 22 + j;   // streamed row index 0..43
            const int sl  = j % 11;          // compile-time acc slot (22%11==0)
            const int cur = j & 1;           // compile-time parity (22 even)
            const int nxt = cur ^ 1;

            // Register-prefetch next row's globals (hidden under this row's math).
            float na0 = 0.f, nb0 = 0.f, na1 = 0.f, nb1 = 0.f;
            const bool notlast = !(half == 1 && j == 21);
            if (notlast) {
                const int rn = y0 - 4 + i;
                if (rn >= 0 && rn < H_) {
                    const int ro = rn * W_;
                    if (vm) { na0 = p1[ro + gxm]; nb0 = p2[ro + gxm]; }
                    if (vh) { na1 = p1[ro + gxh]; nb1 = p2[ro + gxh]; }
                }
            }

            // Horizontal 11-tap pass over 5 fields from LDS buffer `cur`.
            float s1 = 0.f, s2 = 0.f, s11 = 0.f, s22 = 0.f, s12 = 0.f;
            #pragma unroll
            for (int t = 0; t < 11; ++t) {
                const float2 v = rowbuf[w][cur][lane + t];
                const float ga = G[t] * v.x;
                const float gb = G[t] * v.y;
                s1 += ga;
                s2 += gb;
                s11 = fmaf(ga, v.x, s11);
                s22 = fmaf(gb, v.y, s22);
                s12 = fmaf(ga, v.y, s12);
            }

            // Vertical accumulation into the 11 pending outputs (static slots).
            #pragma unroll
            for (int m = 0; m < 11; ++m) {
                const int s = (sl + m) % 11;
                const float gw = G[10 - m];
                acc[s][0] = fmaf(gw, s1,  acc[s][0]);
                acc[s][1] = fmaf(gw, s2,  acc[s][1]);
                acc[s][2] = fmaf(gw, s11, acc[s][2]);
                acc[s][3] = fmaf(gw, s22, acc[s][3]);
                acc[s][4] = fmaf(gw, s12, acc[s][4]);
            }

            // Output row o = y0 + i - 10 completes in slot sl at i >= 10.
            if (half > 0 || j >= 10) {
                const int o = y0 + i - 10;
                if (o < H_) {                // ragged last strip guard
                    const float mu1 = acc[sl][0], mu2 = acc[sl][1];
                    const float x11 = acc[sl][2], x22 = acc[sl][3], x12 = acc[sl][4];
                    const float mu1s = mu1 * mu1, mu2s = mu2 * mu2, mu12 = mu1 * mu2;
                    const float num = (2.f * mu12 + 1e-4f) * (2.f * (x12 - mu12) + 9e-4f) + 1e-5f;
                    const float den = (mu1s + mu2s + 1e-4f)
                                    * ((x11 - mu1s) + (x22 - mu2s) + 9e-4f) + 1e-5f;
                    psum += __fdividef(num, den);
                }
            }
            // Slot sl is recycled for output o+11: always reset.
            #pragma unroll
            for (int f = 0; f < 5; ++f) acc[sl][f] = 0.f;

            // Stage the prefetched row into the OTHER buffer.
            if (notlast) {
                rowbuf[w][nxt][lane] = make_float2(na0, nb0);
                if (lane < 10) rowbuf[w][nxt][64 + lane] = make_float2(na1, nb1);
            }
            // Fence: next iteration's ds_reads may not move above this point,
            // and this iteration's ds_writes may not move up past the reads.
            __builtin_amdgcn_sched_barrier(0);
            __builtin_amdgcn_wave_barrier();
            __builtin_amdgcn_sched_barrier(0);
        }
    }

    // Wave-local reduction, one atomic per wave (3072 total).
    #pragma unroll
    for (int off = 32; off > 0; off >>= 1) psum += __shfl_xor(psum, off, 64);
    if (lane == 0) atomicAdd(accum, psum);
}

__global__ void ssim_final(const float* __restrict__ accum, float* __restrict__ out) {
    out[0] = 1.0f - accum[0] * (1.0f / 6291456.0f);  // B*C*H*MW = 16*3*512*256
}

extern "C" void kernel_launch(void* const* d_in, const int* in_sizes, int n_in,
                              void* d_out, int out_size, void* d_ws, size_t ws_size,
                              hipStream_t stream) {
    const float* img1 = (const float*)d_in[0];
    const float* img2 = (const float*)d_in[1];
    const int*   pos  = (const int*)d_in[2];
    float* out = (float*)d_out;
    float* acc = (float*)d_ws;

    hipMemsetAsync(acc, 0, sizeof(float), stream);

    // 48 (b,ch) images x 16 row strips; each block = 4 waves = 4 column strips.
    ssim_main<<<B_ * C_ * NRS, 256, 0, stream>>>(img1, img2, pos, acc);
    ssim_final<<<1, 1, 0, stream>>>(acc, out);
}